// Round 1
// baseline (32396.481 us; speedup 1.0000x reference)
//
#include <hip/hip_runtime.h>
#include <hip/hip_cooperative_groups.h>

namespace cg = cooperative_groups;

static constexpr int T_STEPS = 512;
static constexpr int BATCH   = 64;
static constexpr int DIN     = 256;
static constexpr int HID     = 512;
static constexpr int KDIM    = DIN + HID;   // 768
static constexpr int S4      = 193;         // LDS row stride in float4 (192 data + 1 pad)

__device__ __forceinline__ float fast_sigmoid(float v) {
    return 1.0f / (1.0f + __expf(-v));
}
__device__ __forceinline__ float fast_tanh(float v) {
    // 1 - 2/(e^{2v}+1); saturates correctly at +/-inf
    return 1.0f - 2.0f / (__expf(2.0f * v) + 1.0f);
}

// 256 WGs x 512 threads, 1 WG/CU (LDS ~150 KB). Each WG owns:
//   - a batch group of 16 (bgroup 0..3)
//   - a hidden slice of 8 units (kslice 0..63) -> 32 weight rows (f,i,g,o x 8)
// Weights stay in LDS for all 512 steps; c stays in registers; h ping-pongs
// through the hx/cx tail sections of d_out (no d_ws use).
__global__ __launch_bounds__(512, 1)
void lstm_persistent(const float* __restrict__ x,
                     const float* __restrict__ Wf, const float* __restrict__ bfp,
                     const float* __restrict__ Wi, const float* __restrict__ bip,
                     const float* __restrict__ Wg, const float* __restrict__ bgp,
                     const float* __restrict__ Wo, const float* __restrict__ bop,
                     float* __restrict__ out) {
    __shared__ float4 W4[32 * S4];        // 98,816 B: 32 rows x 768 fp32
    __shared__ float4 C4[16 * S4];        // 49,408 B: combined [x|h] for 16 b
    __shared__ float  gates_s[16 * 33];   // pre-activation gates
    __shared__ float  bias_s[32];

    cg::grid_group grid = cg::this_grid();

    const int tid = threadIdx.x;
    const int wg  = blockIdx.x;
    // XCD-aware: blocks mapping to XCD pair {2g,2g+1} share a batch group,
    // so h exchange for a b-group stays within 2 XCDs' L2.
    const int bgroup = (wg & 7) >> 1;                  // 0..3
    const int kslice = ((wg >> 3) << 1) | (wg & 1);    // 0..63
    const int bg0 = bgroup * 16;
    const int k0  = kslice * 8;

    // ---- one-time: stage 32 weight rows (gate*8 + unit) into LDS ----
    {
        const int r    = tid >> 4;     // 0..31
        const int c0   = tid & 15;
        const int gate = r >> 3;       // wave-uniform (4 rows/wave, gate flips every 8)
        const int unit = k0 + (r & 7);
        const float* wsrc = (gate == 0) ? Wf : (gate == 1) ? Wi : (gate == 2) ? Wg : Wo;
        const float4* src4 = (const float4*)(wsrc + (size_t)unit * KDIM);
        #pragma unroll
        for (int m = 0; m < 12; ++m)
            W4[r * S4 + c0 + 16 * m] = src4[c0 + 16 * m];
        if (tid < 32) {
            const int g2 = tid >> 3;
            const float* bsrc = (g2 == 0) ? bfp : (g2 == 1) ? bip : (g2 == 2) ? bgp : bop;
            bias_s[tid] = bsrc[k0 + (tid & 7)];
        }
    }

    float* const hx_sec = out + (size_t)T_STEPS * BATCH * HID;  // h buffer 0 (ends as hx)
    float* const cx_sec = hx_sec + BATCH * HID;                 // h buffer 1 (ends as cx)

    const int lb2 = tid >> 3;   // phase-2 mapping (tid<128): local b
    const int u2  = tid & 7;    //                            local hidden unit

    // zero-init h0 (each WG zeros exactly its own (b,k) slab)
    if (tid < 128)
        hx_sec[(size_t)(bg0 + lb2) * HID + (k0 + u2)] = 0.0f;
    grid.sync();

    // phase-1 mapping: lane strip over K (16 interleaved float4 stripes),
    // 4 batches x 4 rows register tile per thread
    const int lbg = tid >> 7;        // 0..3  -> batches lbg*4..lbg*4+3
    const int rg  = (tid >> 4) & 7;  // 0..7  -> rows rg*4..rg*4+3
    const int kq  = tid & 15;        // 0..15 -> K stripe

    float c_reg = 0.0f;

    for (int t = 0; t < T_STEPS; ++t) {
        const float* h_read  = (t & 1) ? cx_sec : hx_sec;
        float*       h_write = (t & 1) ? hx_sec : cx_sec;

        // ---- stage combined = [x_t | h_{t-1}] for our 16 batches ----
        {
            const float4* xs = (const float4*)(x + ((size_t)t * BATCH + bg0) * DIN);
            #pragma unroll
            for (int m = 0; m < 2; ++m) {
                const int i4 = tid + 512 * m;               // 0..1023 (16b x 64 f4)
                C4[(i4 >> 6) * S4 + (i4 & 63)] = xs[i4];
            }
            const float4* hs = (const float4*)(h_read + (size_t)bg0 * HID);
            #pragma unroll
            for (int m = 0; m < 4; ++m) {
                const int i4 = tid + 512 * m;               // 0..2047 (16b x 128 f4)
                C4[(i4 >> 7) * S4 + 64 + (i4 & 127)] = hs[i4];
            }
        }
        __syncthreads();

        // ---- gates GEMM: 4x4 register tile, K/16 per lane ----
        float acc[4][4];
        #pragma unroll
        for (int i = 0; i < 4; ++i) {
            #pragma unroll
            for (int j = 0; j < 4; ++j) acc[i][j] = 0.0f;
        }

        #pragma unroll
        for (int it = 0; it < 12; ++it) {
            const int dq = kq + 16 * it;                    // f4 column 0..191
            float4 cv[4], wv[4];
            #pragma unroll
            for (int i = 0; i < 4; ++i) cv[i] = C4[(lbg * 4 + i) * S4 + dq];
            #pragma unroll
            for (int j = 0; j < 4; ++j) wv[j] = W4[(rg * 4 + j) * S4 + dq];
            #pragma unroll
            for (int i = 0; i < 4; ++i) {
                #pragma unroll
                for (int j = 0; j < 4; ++j) {
                    acc[i][j] = fmaf(cv[i].x, wv[j].x, acc[i][j]);
                    acc[i][j] = fmaf(cv[i].y, wv[j].y, acc[i][j]);
                    acc[i][j] = fmaf(cv[i].z, wv[j].z, acc[i][j]);
                    acc[i][j] = fmaf(cv[i].w, wv[j].w, acc[i][j]);
                }
            }
        }

        // reduce the 16 K-stripes (lane bits 0..3) via shuffle
        #pragma unroll
        for (int i = 0; i < 4; ++i) {
            #pragma unroll
            for (int j = 0; j < 4; ++j) {
                float v = acc[i][j];
                v += __shfl_xor(v, 1);
                v += __shfl_xor(v, 2);
                v += __shfl_xor(v, 4);
                v += __shfl_xor(v, 8);
                if (kq == 0)
                    gates_s[(lbg * 4 + i) * 33 + (rg * 4 + j)] = v;
            }
        }
        __syncthreads();

        // ---- LSTM cell update (one thread per (b, hidden unit)) ----
        if (tid < 128) {
            const float pf = gates_s[lb2 * 33 + u2]      + bias_s[u2];
            const float pi = gates_s[lb2 * 33 + 8 + u2]  + bias_s[8 + u2];
            const float pg = gates_s[lb2 * 33 + 16 + u2] + bias_s[16 + u2];
            const float po = gates_s[lb2 * 33 + 24 + u2] + bias_s[24 + u2];
            const float fg = fast_sigmoid(pf);
            const float ig = fast_sigmoid(pi);
            const float gg = fast_tanh(pg);
            const float og = fast_sigmoid(po);
            c_reg = fg * c_reg + ig * gg;
            const float h = og * fast_tanh(c_reg);
            const int b = bg0 + lb2;
            const int k = k0 + u2;
            h_write[(size_t)b * HID + k] = h;
            out[((size_t)t * BATCH + b) * HID + k] = h;
        }
        grid.sync();   // h_t visible to all; also protects ping-pong WAR
    }

    // t=511 wrote h into hx_sec (correct final hx). Final grid.sync has
    // retired all reads of cx_sec as h_read, so overwrite it with c.
    if (tid < 128)
        cx_sec[(size_t)(bg0 + lb2) * HID + (k0 + u2)] = c_reg;
}

extern "C" void kernel_launch(void* const* d_in, const int* in_sizes, int n_in,
                              void* d_out, int out_size, void* d_ws, size_t ws_size,
                              hipStream_t stream) {
    (void)in_sizes; (void)n_in; (void)d_ws; (void)ws_size; (void)out_size;
    const float* x  = (const float*)d_in[0];
    const float* Wf = (const float*)d_in[1];
    const float* bf = (const float*)d_in[2];
    const float* Wi = (const float*)d_in[3];
    const float* bi = (const float*)d_in[4];
    const float* Wg = (const float*)d_in[5];
    const float* bg = (const float*)d_in[6];
    const float* Wo = (const float*)d_in[7];
    const float* bo = (const float*)d_in[8];
    float* out = (float*)d_out;

    void* args[] = {&x, &Wf, &bf, &Wi, &bi, &Wg, &bg, &Wo, &bo, &out};
    hipLaunchCooperativeKernel(reinterpret_cast<void*>(lstm_persistent),
                               dim3(256), dim3(512), args, 0, stream);
}

// Round 2
// 29622.189 us; speedup vs baseline: 1.0937x; 1.0937x over previous
//
#include <hip/hip_runtime.h>

static constexpr int T_STEPS = 512;
static constexpr int BATCH   = 64;
static constexpr int DIN     = 256;
static constexpr int HID     = 512;
static constexpr int KDIM    = DIN + HID;   // 768
static constexpr int S4      = 193;         // LDS row stride in float4 (192 data + 1 pad)
static constexpr int NBLK    = 256;

__device__ __forceinline__ float fast_sigmoid(float v) {
    return 1.0f / (1.0f + __expf(-v));
}
__device__ __forceinline__ float fast_tanh(float v) {
    return 1.0f - 2.0f / (__expf(2.0f * v) + 1.0f);
}

// Monotonic-generation grid barrier. cnt starts at 0 (memset by host, async).
// Leader: RELEASE fetch_add (compiler emits vmcnt drain + buffer_wbl2 sc1 ->
// all this WG's h stores, already drained to L2 by the preceding s_barrier,
// become device-visible). Poll with RELAXED agent loads (sc0/sc1, no cache
// pollution, no per-poll invalidate), then one acquire fence (__threadfence:
// buffer_inv) so the whole CU's L1 / XCD L2 drop stale h lines.
__device__ __forceinline__ void grid_barrier(unsigned* __restrict__ cnt, unsigned gen) {
    __syncthreads();   // all waves' h stores drained (vmcnt(0) before s_barrier)
    if (threadIdx.x == 0) {
        __hip_atomic_fetch_add(cnt, 1u, __ATOMIC_RELEASE, __HIP_MEMORY_SCOPE_AGENT);
        const unsigned target = gen * (unsigned)NBLK;
        while (__hip_atomic_load(cnt, __ATOMIC_RELAXED, __HIP_MEMORY_SCOPE_AGENT) < target) {
            __builtin_amdgcn_s_sleep(1);
        }
        __threadfence();   // acquire: invalidate stale L1/L2 lines
    }
    __syncthreads();   // rest of block waits for leader; also a compiler fence
}

// 256 WGs x 512 threads, 1 WG/CU. Each WG owns a batch group of 16 and a
// hidden slice of 8 units (32 stacked gate rows, LDS-resident all 512 steps).
// c stays in registers; h ping-pongs through the hx/cx tail of d_out.
__global__ __launch_bounds__(512, 1)
void lstm_persistent(const float* __restrict__ x,
                     const float* __restrict__ Wf, const float* __restrict__ bfp,
                     const float* __restrict__ Wi, const float* __restrict__ bip,
                     const float* __restrict__ Wg, const float* __restrict__ bgp,
                     const float* __restrict__ Wo, const float* __restrict__ bop,
                     float* __restrict__ out, unsigned* __restrict__ barrier_cnt) {
    __shared__ float4 W4[32 * S4];        // 32 rows x 768 fp32
    __shared__ float4 C4[16 * S4];        // combined [x|h] for 16 b
    __shared__ float  gates_s[16 * 33];
    __shared__ float  bias_s[32];

    const int tid = threadIdx.x;
    const int wg  = blockIdx.x;
    // XCD-aware: round-robin dispatch puts {2g,2g+1} XCDs on one batch group.
    const int bgroup = (wg & 7) >> 1;                  // 0..3
    const int kslice = ((wg >> 3) << 1) | (wg & 1);    // 0..63
    const int bg0 = bgroup * 16;
    const int k0  = kslice * 8;

    // ---- one-time: stage 32 weight rows (gate*8 + unit) into LDS ----
    {
        const int r    = tid >> 4;     // 0..31
        const int c0   = tid & 15;
        const int gate = r >> 3;
        const int unit = k0 + (r & 7);
        const float* wsrc = (gate == 0) ? Wf : (gate == 1) ? Wi : (gate == 2) ? Wg : Wo;
        const float4* src4 = (const float4*)(wsrc + (size_t)unit * KDIM);
        #pragma unroll
        for (int m = 0; m < 12; ++m)
            W4[r * S4 + c0 + 16 * m] = src4[c0 + 16 * m];
        if (tid < 32) {
            const int g2 = tid >> 3;
            const float* bsrc = (g2 == 0) ? bfp : (g2 == 1) ? bip : (g2 == 2) ? bgp : bop;
            bias_s[tid] = bsrc[k0 + (tid & 7)];
        }
    }

    float* const hx_sec = out + (size_t)T_STEPS * BATCH * HID;  // h buf 0 (ends as hx)
    float* const cx_sec = hx_sec + BATCH * HID;                 // h buf 1 (ends as cx)

    const int lb2 = tid >> 3;   // cell-update mapping (tid<128)
    const int u2  = tid & 7;

    // zero-init h0 (each WG zeros exactly its own (b,k) slab)
    if (tid < 128)
        hx_sec[(size_t)(bg0 + lb2) * HID + (k0 + u2)] = 0.0f;
    unsigned gen = 1;
    grid_barrier(barrier_cnt, gen++);

    // GEMM mapping: lane strip over K (16 interleaved f4 stripes), 4x4 tile
    const int lbg = tid >> 7;        // 0..3  -> batches lbg*4..+3
    const int rg  = (tid >> 4) & 7;  // 0..7  -> rows rg*4..+3
    const int kq  = tid & 15;        // 0..15 -> K stripe

    float c_reg = 0.0f;

    for (int t = 0; t < T_STEPS; ++t) {
        const float* h_read  = (t & 1) ? cx_sec : hx_sec;
        float*       h_write = (t & 1) ? hx_sec : cx_sec;

        // ---- stage combined = [x_t | h_{t-1}] for our 16 batches ----
        {
            const float4* xs = (const float4*)(x + ((size_t)t * BATCH + bg0) * DIN);
            #pragma unroll
            for (int m = 0; m < 2; ++m) {
                const int i4 = tid + 512 * m;               // 16b x 64 f4
                C4[(i4 >> 6) * S4 + (i4 & 63)] = xs[i4];
            }
            const float4* hs = (const float4*)(h_read + (size_t)bg0 * HID);
            #pragma unroll
            for (int m = 0; m < 4; ++m) {
                const int i4 = tid + 512 * m;               // 16b x 128 f4
                C4[(i4 >> 7) * S4 + 64 + (i4 & 127)] = hs[i4];
            }
        }
        __syncthreads();

        // ---- gates GEMM: 4x4 register tile, K/16 per lane ----
        float acc[4][4];
        #pragma unroll
        for (int i = 0; i < 4; ++i)
            #pragma unroll
            for (int j = 0; j < 4; ++j) acc[i][j] = 0.0f;

        #pragma unroll
        for (int it = 0; it < 12; ++it) {
            const int dq = kq + 16 * it;
            float4 cv[4], wv[4];
            #pragma unroll
            for (int i = 0; i < 4; ++i) cv[i] = C4[(lbg * 4 + i) * S4 + dq];
            #pragma unroll
            for (int j = 0; j < 4; ++j) wv[j] = W4[(rg * 4 + j) * S4 + dq];
            #pragma unroll
            for (int i = 0; i < 4; ++i) {
                #pragma unroll
                for (int j = 0; j < 4; ++j) {
                    acc[i][j] = fmaf(cv[i].x, wv[j].x, acc[i][j]);
                    acc[i][j] = fmaf(cv[i].y, wv[j].y, acc[i][j]);
                    acc[i][j] = fmaf(cv[i].z, wv[j].z, acc[i][j]);
                    acc[i][j] = fmaf(cv[i].w, wv[j].w, acc[i][j]);
                }
            }
        }

        // reduce the 16 K-stripes via shuffle
        #pragma unroll
        for (int i = 0; i < 4; ++i) {
            #pragma unroll
            for (int j = 0; j < 4; ++j) {
                float v = acc[i][j];
                v += __shfl_xor(v, 1);
                v += __shfl_xor(v, 2);
                v += __shfl_xor(v, 4);
                v += __shfl_xor(v, 8);
                if (kq == 0)
                    gates_s[(lbg * 4 + i) * 33 + (rg * 4 + j)] = v;
            }
        }
        __syncthreads();

        // ---- LSTM cell update (one thread per (b, hidden unit)) ----
        if (tid < 128) {
            const float pf = gates_s[lb2 * 33 + u2]      + bias_s[u2];
            const float pi = gates_s[lb2 * 33 + 8 + u2]  + bias_s[8 + u2];
            const float pg = gates_s[lb2 * 33 + 16 + u2] + bias_s[16 + u2];
            const float po = gates_s[lb2 * 33 + 24 + u2] + bias_s[24 + u2];
            const float fg = fast_sigmoid(pf);
            const float ig = fast_sigmoid(pi);
            const float gg = fast_tanh(pg);
            const float og = fast_sigmoid(po);
            c_reg = fg * c_reg + ig * gg;
            const float h = og * fast_tanh(c_reg);
            const int b = bg0 + lb2;
            const int k = k0 + u2;
            h_write[(size_t)b * HID + k] = h;
            out[((size_t)t * BATCH + b) * HID + k] = h;
        }
        grid_barrier(barrier_cnt, gen++);   // h_t visible grid-wide; WAR safe
    }

    // final: hx already in hx_sec (t=511 wrote it); overwrite cx_sec with c.
    // Last grid_barrier retired all step-511 reads of cx_sec. Kernel-end
    // completion flushes these stores.
    if (tid < 128)
        cx_sec[(size_t)(bg0 + lb2) * HID + (k0 + u2)] = c_reg;
}

extern "C" void kernel_launch(void* const* d_in, const int* in_sizes, int n_in,
                              void* d_out, int out_size, void* d_ws, size_t ws_size,
                              hipStream_t stream) {
    (void)in_sizes; (void)n_in; (void)ws_size; (void)out_size;
    const float* x  = (const float*)d_in[0];
    const float* Wf = (const float*)d_in[1];
    const float* bf = (const float*)d_in[2];
    const float* Wi = (const float*)d_in[3];
    const float* bi = (const float*)d_in[4];
    const float* Wg = (const float*)d_in[5];
    const float* bg = (const float*)d_in[6];
    const float* Wo = (const float*)d_in[7];
    const float* bo = (const float*)d_in[8];
    float* out = (float*)d_out;
    unsigned* cnt = (unsigned*)d_ws;

    // barrier counter must start at 0 (d_ws is poisoned 0xAA each call)
    hipMemsetAsync(d_ws, 0, 64, stream);

    void* args[] = {&x, &Wf, &bf, &Wi, &bi, &Wg, &bg, &Wo, &bo, &out, &cnt};
    hipLaunchCooperativeKernel(reinterpret_cast<void*>(lstm_persistent),
                               dim3(NBLK), dim3(512), args, 0, stream);
}

// Round 3
// 27728.732 us; speedup vs baseline: 1.1683x; 1.0683x over previous
//
#include <hip/hip_runtime.h>

static constexpr int T_STEPS = 512;
static constexpr int BATCH   = 64;
static constexpr int DIN     = 256;
static constexpr int HID     = 512;
static constexpr int KDIM    = DIN + HID;   // 768
static constexpr int S4      = 193;         // LDS row stride in float4 (192 data + 1 pad)
static constexpr int NBLK    = 256;

__device__ __forceinline__ float fast_sigmoid(float v) {
    return 1.0f / (1.0f + __expf(-v));
}
__device__ __forceinline__ float fast_tanh(float v) {
    return 1.0f - 2.0f / (__expf(2.0f * v) + 1.0f);
}

// Wait until all 64 producer flags of this bgroup reach `target`.
// Wave 0: one flag per lane (2 cache lines total, plain read-only loads —
// no RMW, no line ownership ping-pong), divergent spin until every lane's
// flag arrives, then a single agent-acquire fence (L1/L2 inv) so the
// subsequent h reads see remote XCDs' data. Other waves park at s_barrier.
__device__ __forceinline__ void wait_flags(const unsigned* __restrict__ flg,
                                           unsigned target) {
    if (threadIdx.x < 64) {
        unsigned v = __hip_atomic_load(&flg[threadIdx.x], __ATOMIC_RELAXED,
                                       __HIP_MEMORY_SCOPE_AGENT);
        while (v < target) {
            __builtin_amdgcn_s_sleep(1);
            v = __hip_atomic_load(&flg[threadIdx.x], __ATOMIC_RELAXED,
                                  __HIP_MEMORY_SCOPE_AGENT);
        }
        __builtin_amdgcn_fence(__ATOMIC_ACQUIRE, "agent");
    }
    __syncthreads();
}

// 256 WGs x 512 threads, 1 WG/CU. Each WG: batch group of 16 (bgroup 0..3),
// hidden slice of 8 units (kslice 0..63). Weights LDS-resident all 512 steps;
// c in registers; h ping-pongs through the hx/cx tail of d_out.
// Sync: per-bgroup producer flags (release STORE per WG per step, zero RMWs).
__global__ __launch_bounds__(512, 1)
void lstm_persistent(const float* __restrict__ x,
                     const float* __restrict__ Wf, const float* __restrict__ bfp,
                     const float* __restrict__ Wi, const float* __restrict__ bip,
                     const float* __restrict__ Wg, const float* __restrict__ bgp,
                     const float* __restrict__ Wo, const float* __restrict__ bop,
                     float* __restrict__ out, unsigned* __restrict__ flags_ws) {
    __shared__ float4 W4[32 * S4];        // 32 rows x 768 fp32
    __shared__ float4 C4[16 * S4];        // combined [x|h] for 16 b
    __shared__ float  gates_s[16 * 33];
    __shared__ float  bias_s[32];

    const int tid = threadIdx.x;
    const int wg  = blockIdx.x;
    // Round-robin dispatch: bgroup g lives on XCD pair {2g,2g+1}.
    const int bgroup = (wg & 7) >> 1;                  // 0..3
    const int kslice = ((wg >> 3) << 1) | (wg & 1);    // 0..63
    const int bg0 = bgroup * 16;
    const int k0  = kslice * 8;

    unsigned* const flg = flags_ws + bgroup * 128;     // groups 512 B apart

    // ---- one-time: stage 32 weight rows (gate*8 + unit) into LDS ----
    {
        const int r    = tid >> 4;     // 0..31
        const int c0   = tid & 15;
        const int gate = r >> 3;
        const int unit = k0 + (r & 7);
        const float* wsrc = (gate == 0) ? Wf : (gate == 1) ? Wi : (gate == 2) ? Wg : Wo;
        const float4* src4 = (const float4*)(wsrc + (size_t)unit * KDIM);
        #pragma unroll
        for (int m = 0; m < 12; ++m)
            W4[r * S4 + c0 + 16 * m] = src4[c0 + 16 * m];
        if (tid < 32) {
            const int g2 = tid >> 3;
            const float* bsrc = (g2 == 0) ? bfp : (g2 == 1) ? bip : (g2 == 2) ? bgp : bop;
            bias_s[tid] = bsrc[k0 + (tid & 7)];
        }
    }

    float* const hx_sec = out + (size_t)T_STEPS * BATCH * HID;  // buf0 (h_0,h_2,.. -> hx)
    float* const cx_sec = hx_sec + BATCH * HID;                 // buf1 (h_1,h_3,.. -> cx)

    const int lb2 = tid >> 3;   // cell-update mapping (tid<128)
    const int u2  = tid & 7;

    // zero h0 slab, publish flag=1 ("h_0 ready")
    if (tid < 128)
        hx_sec[(size_t)(bg0 + lb2) * HID + (k0 + u2)] = 0.0f;
    __syncthreads();
    if (tid == 0)
        __hip_atomic_store(&flg[kslice], 1u, __ATOMIC_RELEASE,
                           __HIP_MEMORY_SCOPE_AGENT);

    // GEMM mapping: lane strip over K (16 interleaved f4 stripes), 4x4 tile
    const int lbg = tid >> 7;        // 0..3  -> batches lbg*4..+3
    const int rg  = (tid >> 4) & 7;  // 0..7  -> rows rg*4..+3
    const int kq  = tid & 15;        // 0..15 -> K stripe

    float c_reg = 0.0f;

    for (int t = 0; t < T_STEPS; ++t) {
        const float* h_read  = (t & 1) ? cx_sec : hx_sec;   // h_t in buf[t&1]
        float*       h_write = (t & 1) ? hx_sec : cx_sec;   // h_{t+1} -> buf[(t+1)&1]

        // ---- A: stage x_t (flag-independent; loads hide behind the poll) ----
        {
            const float4* xs = (const float4*)(x + ((size_t)t * BATCH + bg0) * DIN);
            #pragma unroll
            for (int m = 0; m < 2; ++m) {
                const int i4 = tid + 512 * m;               // 16b x 64 f4
                C4[(i4 >> 6) * S4 + (i4 & 63)] = xs[i4];
            }
        }

        // ---- B: wait until all peers published h_t ----
        wait_flags(flg, (unsigned)(t + 1));

        // ---- C: stage h_t ----
        {
            const float4* hs = (const float4*)(h_read + (size_t)bg0 * HID);
            #pragma unroll
            for (int m = 0; m < 4; ++m) {
                const int i4 = tid + 512 * m;               // 16b x 128 f4
                C4[(i4 >> 7) * S4 + 64 + (i4 & 127)] = hs[i4];
            }
        }
        __syncthreads();

        // ---- D: gates GEMM: 4x4 register tile, K/16 per lane ----
        float acc[4][4];
        #pragma unroll
        for (int i = 0; i < 4; ++i)
            #pragma unroll
            for (int j = 0; j < 4; ++j) acc[i][j] = 0.0f;

        #pragma unroll
        for (int it = 0; it < 12; ++it) {
            const int dq = kq + 16 * it;
            float4 cv[4], wv[4];
            #pragma unroll
            for (int i = 0; i < 4; ++i) cv[i] = C4[(lbg * 4 + i) * S4 + dq];
            #pragma unroll
            for (int j = 0; j < 4; ++j) wv[j] = W4[(rg * 4 + j) * S4 + dq];
            #pragma unroll
            for (int i = 0; i < 4; ++i) {
                #pragma unroll
                for (int j = 0; j < 4; ++j) {
                    acc[i][j] = fmaf(cv[i].x, wv[j].x, acc[i][j]);
                    acc[i][j] = fmaf(cv[i].y, wv[j].y, acc[i][j]);
                    acc[i][j] = fmaf(cv[i].z, wv[j].z, acc[i][j]);
                    acc[i][j] = fmaf(cv[i].w, wv[j].w, acc[i][j]);
                }
            }
        }

        // ---- E: reduce 16 K-stripes via shuffle, park in LDS ----
        #pragma unroll
        for (int i = 0; i < 4; ++i) {
            #pragma unroll
            for (int j = 0; j < 4; ++j) {
                float v = acc[i][j];
                v += __shfl_xor(v, 1);
                v += __shfl_xor(v, 2);
                v += __shfl_xor(v, 4);
                v += __shfl_xor(v, 8);
                if (kq == 0)
                    gates_s[(lbg * 4 + i) * 33 + (rg * 4 + j)] = v;
            }
        }
        __syncthreads();

        // ---- F: LSTM cell update (one thread per (b, hidden unit)) ----
        if (tid < 128) {
            const float pf = gates_s[lb2 * 33 + u2]      + bias_s[u2];
            const float pi = gates_s[lb2 * 33 + 8 + u2]  + bias_s[8 + u2];
            const float pg = gates_s[lb2 * 33 + 16 + u2] + bias_s[16 + u2];
            const float po = gates_s[lb2 * 33 + 24 + u2] + bias_s[24 + u2];
            const float fg = fast_sigmoid(pf);
            const float ig = fast_sigmoid(pi);
            const float gg = fast_tanh(pg);
            const float og = fast_sigmoid(po);
            c_reg = fg * c_reg + ig * gg;
            const float h = og * fast_tanh(c_reg);
            const int b = bg0 + lb2;
            const int k = k0 + u2;
            h_write[(size_t)b * HID + k] = h;
            out[((size_t)t * BATCH + b) * HID + k] = h;
        }
        __syncthreads();   // F's stores (waves 0-1) drained to L2 before release

        // ---- G: publish h_{t+1} (single release STORE — no RMW) ----
        if (tid == 0)
            __hip_atomic_store(&flg[kslice], (unsigned)(t + 2), __ATOMIC_RELEASE,
                               __HIP_MEMORY_SCOPE_AGENT);
    }

    // Final: hx (h_512) already in hx_sec. Overwrite buf1 (h_511) with c only
    // after all peers finished step 511 (flag=T+1 implies done reading h_511).
    wait_flags(flg, (unsigned)(T_STEPS + 1));
    if (tid < 128)
        cx_sec[(size_t)(bg0 + lb2) * HID + (k0 + u2)] = c_reg;
}

extern "C" void kernel_launch(void* const* d_in, const int* in_sizes, int n_in,
                              void* d_out, int out_size, void* d_ws, size_t ws_size,
                              hipStream_t stream) {
    (void)in_sizes; (void)n_in; (void)ws_size; (void)out_size;
    const float* x  = (const float*)d_in[0];
    const float* Wf = (const float*)d_in[1];
    const float* bf = (const float*)d_in[2];
    const float* Wi = (const float*)d_in[3];
    const float* bi = (const float*)d_in[4];
    const float* Wg = (const float*)d_in[5];
    const float* bg = (const float*)d_in[6];
    const float* Wo = (const float*)d_in[7];
    const float* bo = (const float*)d_in[8];
    float* out = (float*)d_out;
    unsigned* flags = (unsigned*)d_ws;

    // flags[4][128] (512 B per bgroup) must start at 0 (d_ws poisoned 0xAA)
    hipMemsetAsync(d_ws, 0, 4 * 128 * sizeof(unsigned), stream);

    void* args[] = {&x, &Wf, &bf, &Wi, &bi, &Wg, &bg, &Wo, &bo, &out, &flags};
    hipLaunchCooperativeKernel(reinterpret_cast<void*>(lstm_persistent),
                               dim3(NBLK), dim3(512), args, 0, stream);
}

// Round 4
// 24051.891 us; speedup vs baseline: 1.3469x; 1.1529x over previous
//
#include <hip/hip_runtime.h>

static constexpr int T_STEPS = 512;
static constexpr int BATCH   = 64;
static constexpr int DIN     = 256;
static constexpr int HID     = 512;
static constexpr int KDIM    = DIN + HID;   // 768
static constexpr int S4      = 193;         // LDS row stride in float4 (192 data + 1 pad)
static constexpr int NBLK    = 256;

__device__ __forceinline__ float fast_sigmoid(float v) {
    return 1.0f / (1.0f + __expf(-v));
}
__device__ __forceinline__ float fast_tanh(float v) {
    return 1.0f - 2.0f / (__expf(2.0f * v) + 1.0f);
}

// Relaxed agent-scope ops: global_load/store with sc0 sc1 (L1+L2 bypass,
// served at MALL = device coherence point). NO buffer_wbl2 / buffer_inv —
// that full-L2 writeback+invalidate per WG per step was rounds 1-3's 50 us.
__device__ __forceinline__ void store_bypass(float* p, float v) {
    __hip_atomic_store((unsigned int*)p, __float_as_uint(v),
                       __ATOMIC_RELAXED, __HIP_MEMORY_SCOPE_AGENT);
}
__device__ __forceinline__ float load_bypass(const float* p) {
    return __uint_as_float(__hip_atomic_load((const unsigned int*)p,
                           __ATOMIC_RELAXED, __HIP_MEMORY_SCOPE_AGENT));
}

// Wait until all 64 producer flags of this bgroup reach `target`.
// Pure bypass loads (always coherent at MALL) -> no acquire fence needed.
__device__ __forceinline__ void wait_flags(const unsigned* __restrict__ flg,
                                           unsigned target) {
    if (threadIdx.x < 64) {
        unsigned v = __hip_atomic_load(&flg[threadIdx.x], __ATOMIC_RELAXED,
                                       __HIP_MEMORY_SCOPE_AGENT);
        while (v < target) {
            __builtin_amdgcn_s_sleep(1);
            v = __hip_atomic_load(&flg[threadIdx.x], __ATOMIC_RELAXED,
                                  __HIP_MEMORY_SCOPE_AGENT);
        }
    }
    __syncthreads();   // also a full compiler barrier: gather can't hoist above
}

// 256 WGs x 512 threads, 1 WG/CU. Each WG: batch group of 16 (bgroup 0..3),
// hidden slice of 8 units (kslice 0..63). Weights LDS-resident all 512 steps;
// c in registers; h ping-pongs through the hx/cx tail of d_out, accessed
// EXCLUSIVELY via MALL-bypass ops during the recurrence (no cached copies can
// exist: pre-kernel poison was flushed by the memset kernel's end-of-kernel
// release, and we never touch those lines with cached ops until the end).
__global__ __launch_bounds__(512, 1)
void lstm_persistent(const float* __restrict__ x,
                     const float* __restrict__ Wf, const float* __restrict__ bfp,
                     const float* __restrict__ Wi, const float* __restrict__ bip,
                     const float* __restrict__ Wg, const float* __restrict__ bgp,
                     const float* __restrict__ Wo, const float* __restrict__ bop,
                     float* __restrict__ out, unsigned* __restrict__ flags_ws) {
    __shared__ float4 W4[32 * S4];        // 32 rows x 768 fp32
    __shared__ float4 C4[16 * S4];        // combined [x|h] for 16 b
    __shared__ float  gates_s[16 * 33];
    __shared__ float  bias_s[32];

    const int tid = threadIdx.x;
    const int wg  = blockIdx.x;
    // Round-robin dispatch heuristic: bgroup g on XCD pair {2g,2g+1} (perf only).
    const int bgroup = (wg & 7) >> 1;                  // 0..3
    const int kslice = ((wg >> 3) << 1) | (wg & 1);    // 0..63
    const int bg0 = bgroup * 16;
    const int k0  = kslice * 8;

    unsigned* const flg = flags_ws + bgroup * 128;     // groups 512 B apart

    // ---- one-time: stage 32 weight rows (gate*8 + unit) into LDS ----
    {
        const int r    = tid >> 4;     // 0..31
        const int c0   = tid & 15;
        const int gate = r >> 3;
        const int unit = k0 + (r & 7);
        const float* wsrc = (gate == 0) ? Wf : (gate == 1) ? Wi : (gate == 2) ? Wg : Wo;
        const float4* src4 = (const float4*)(wsrc + (size_t)unit * KDIM);
        #pragma unroll
        for (int m = 0; m < 12; ++m)
            W4[r * S4 + c0 + 16 * m] = src4[c0 + 16 * m];
        if (tid < 32) {
            const int g2 = tid >> 3;
            const float* bsrc = (g2 == 0) ? bfp : (g2 == 1) ? bip : (g2 == 2) ? bgp : bop;
            bias_s[tid] = bsrc[k0 + (tid & 7)];
        }
    }

    float* const hx_sec = out + (size_t)T_STEPS * BATCH * HID;  // buf0 (ends as hx)
    float* const cx_sec = hx_sec + BATCH * HID;                 // buf1 (ends as cx)

    const int lb2 = tid >> 3;   // cell-update mapping (tid<128)
    const int u2  = tid & 7;

    // zero h0 slab via bypass stores, publish flag=1 ("h_0 ready").
    // __syncthreads drains vmcnt(0) before s_barrier -> stores at MALL first.
    if (tid < 128)
        store_bypass(&hx_sec[(size_t)(bg0 + lb2) * HID + (k0 + u2)], 0.0f);
    __syncthreads();
    if (tid == 0)
        __hip_atomic_store(&flg[kslice], 1u, __ATOMIC_RELAXED,
                           __HIP_MEMORY_SCOPE_AGENT);

    // GEMM mapping: lane strip over K (16 interleaved f4 stripes), 4x4 tile
    const int lbg = tid >> 7;        // 0..3  -> batches lbg*4..+3
    const int rg  = (tid >> 4) & 7;  // 0..7  -> rows rg*4..+3
    const int kq  = tid & 15;        // 0..15 -> K stripe

    float c_reg = 0.0f;

    for (int t = 0; t < T_STEPS; ++t) {
        const float* h_read  = (t & 1) ? cx_sec : hx_sec;   // h_t in buf[t&1]
        float*       h_write = (t & 1) ? hx_sec : cx_sec;   // h_{t+1} -> buf[(t+1)&1]

        // ---- A: stage x_t (flag-independent; hides behind the poll) ----
        {
            const float4* xs = (const float4*)(x + ((size_t)t * BATCH + bg0) * DIN);
            #pragma unroll
            for (int m = 0; m < 2; ++m) {
                const int i4 = tid + 512 * m;               // 16b x 64 f4
                C4[(i4 >> 6) * S4 + (i4 & 63)] = xs[i4];
            }
        }

        // ---- B: wait until all peers published h_t ----
        wait_flags(flg, (unsigned)(t + 1));

        // ---- C: gather h_t via bypass loads (batch m, element tid) ----
        {
            const float* hsrc = h_read + (size_t)bg0 * HID;
            float hv[16];
            #pragma unroll
            for (int m = 0; m < 16; ++m)
                hv[m] = load_bypass(&hsrc[512 * m + tid]);
            float* Cf = (float*)C4;
            #pragma unroll
            for (int m = 0; m < 16; ++m)
                Cf[m * (S4 * 4) + 256 + tid] = hv[m];   // consecutive dwords: conflict-free
        }
        __syncthreads();

        // ---- D: gates GEMM: 4x4 register tile, K/16 per lane ----
        float acc[4][4];
        #pragma unroll
        for (int i = 0; i < 4; ++i)
            #pragma unroll
            for (int j = 0; j < 4; ++j) acc[i][j] = 0.0f;

        #pragma unroll
        for (int it = 0; it < 12; ++it) {
            const int dq = kq + 16 * it;
            float4 cv[4], wv[4];
            #pragma unroll
            for (int i = 0; i < 4; ++i) cv[i] = C4[(lbg * 4 + i) * S4 + dq];
            #pragma unroll
            for (int j = 0; j < 4; ++j) wv[j] = W4[(rg * 4 + j) * S4 + dq];
            #pragma unroll
            for (int i = 0; i < 4; ++i) {
                #pragma unroll
                for (int j = 0; j < 4; ++j) {
                    acc[i][j] = fmaf(cv[i].x, wv[j].x, acc[i][j]);
                    acc[i][j] = fmaf(cv[i].y, wv[j].y, acc[i][j]);
                    acc[i][j] = fmaf(cv[i].z, wv[j].z, acc[i][j]);
                    acc[i][j] = fmaf(cv[i].w, wv[j].w, acc[i][j]);
                }
            }
        }

        // ---- E: reduce 16 K-stripes via shuffle, park in LDS ----
        #pragma unroll
        for (int i = 0; i < 4; ++i) {
            #pragma unroll
            for (int j = 0; j < 4; ++j) {
                float v = acc[i][j];
                v += __shfl_xor(v, 1);
                v += __shfl_xor(v, 2);
                v += __shfl_xor(v, 4);
                v += __shfl_xor(v, 8);
                if (kq == 0)
                    gates_s[(lbg * 4 + i) * 33 + (rg * 4 + j)] = v;
            }
        }
        __syncthreads();

        // ---- F: LSTM cell update (one thread per (b, hidden unit)) ----
        if (tid < 128) {
            const float pf = gates_s[lb2 * 33 + u2]      + bias_s[u2];
            const float pi = gates_s[lb2 * 33 + 8 + u2]  + bias_s[8 + u2];
            const float pg = gates_s[lb2 * 33 + 16 + u2] + bias_s[16 + u2];
            const float po = gates_s[lb2 * 33 + 24 + u2] + bias_s[24 + u2];
            const float fg = fast_sigmoid(pf);
            const float ig = fast_sigmoid(pi);
            const float gg = fast_tanh(pg);
            const float og = fast_sigmoid(po);
            c_reg = fg * c_reg + ig * gg;
            const float h = og * fast_tanh(c_reg);
            const int b = bg0 + lb2;
            const int k = k0 + u2;
            store_bypass(&h_write[(size_t)b * HID + k], h);   // MALL-direct
            out[((size_t)t * BATCH + b) * HID + k] = h;       // cached, flushed at end
        }
        __syncthreads();   // drains vmcnt(0): h bypass stores visible at MALL

        // ---- G: publish h_{t+1} (bypass store, ordered after F by barrier) ----
        if (tid == 0)
            __hip_atomic_store(&flg[kslice], (unsigned)(t + 2), __ATOMIC_RELAXED,
                               __HIP_MEMORY_SCOPE_AGENT);
    }

    // Final: hx (h_512) already at MALL in hx_sec. Overwrite buf1 (h_511) with
    // c only after all peers finished step 511 (flag=T+1 => done reading h_511).
    // Normal stores: flushed by end-of-kernel release; no bypass reads remain.
    wait_flags(flg, (unsigned)(T_STEPS + 1));
    if (tid < 128)
        cx_sec[(size_t)(bg0 + lb2) * HID + (k0 + u2)] = c_reg;
}

extern "C" void kernel_launch(void* const* d_in, const int* in_sizes, int n_in,
                              void* d_out, int out_size, void* d_ws, size_t ws_size,
                              hipStream_t stream) {
    (void)in_sizes; (void)n_in; (void)ws_size; (void)out_size;
    const float* x  = (const float*)d_in[0];
    const float* Wf = (const float*)d_in[1];
    const float* bf = (const float*)d_in[2];
    const float* Wi = (const float*)d_in[3];
    const float* bi = (const float*)d_in[4];
    const float* Wg = (const float*)d_in[5];
    const float* bg = (const float*)d_in[6];
    const float* Wo = (const float*)d_in[7];
    const float* bo = (const float*)d_in[8];
    float* out = (float*)d_out;
    unsigned* flags = (unsigned*)d_ws;

    // flags[4][128] (512 B per bgroup) must start at 0 (d_ws poisoned 0xAA)
    hipMemsetAsync(d_ws, 0, 4 * 128 * sizeof(unsigned), stream);

    void* args[] = {&x, &Wf, &bf, &Wi, &bi, &Wg, &bg, &Wo, &bo, &out, &flags};
    hipLaunchCooperativeKernel(reinterpret_cast<void*>(lstm_persistent),
                               dim3(NBLK), dim3(512), args, 0, stream);
}